// Round 13
// baseline (87.455 us; speedup 1.0000x reference)
//
#include <hip/hip_runtime.h>

// ---------------------------------------------------------------------------
// MalConvLowMem as GEMM: M=15748 windows (4096 contiguous floats), N=256
// (w1|w2), K=4096; epilogue g=(c1+b1)*sigmoid(c2+b2), max over positions.
// R13 = R12 structure at BM=32 x 2 blocks/CU. 512 thr / 8 waves, wave tile
// 32x32 (acc[2][2] via 16x16 MFMA, same-lane gate pairing from R11).
// A in LDS ring-8 (4KB/slot, 32KB), superstep = 2 K-tiles per
// lgkmcnt(14)+s_barrier (write slot s+4 at step s; 15 newer DS ops by the
// 2nd barrier -> counted wait retires it before its read). B in regs,
// fragment-major (R11 pack_w). Grid 496 = 4 batches x 124 blocks ->
// ~2 blocks/CU; __launch_bounds__(512,4) caps VGPR at 128.
// ---------------------------------------------------------------------------

#define T_LEN 2000000
#define P_CNT 3937
#define M_TOT 15748
#define KD    4096

typedef __attribute__((ext_vector_type(8))) short short8;
typedef __attribute__((ext_vector_type(4))) float f32x4;

static __device__ __forceinline__ unsigned short f2bf(float f) {
    unsigned u = __builtin_bit_cast(unsigned, f);
    unsigned r = (u + 0x7FFFu + ((u >> 16) & 1u)) >> 16;   // RNE
    return (unsigned short)r;
}

static __device__ __forceinline__ unsigned ordenc(float f) {
    unsigned u = __builtin_bit_cast(unsigned, f);
    return (u & 0x80000000u) ? ~u : (u | 0x80000000u);
}

// (batch bb, position p<=3936) -> flat float offset of window start in x
static __device__ __forceinline__ size_t row_base_bp(int bb, int p) {
    int j, kp;
    if (p < 3875) { j = p / 125; kp = p - j * 125; }
    else          { j = 31;      kp = p - 3875; }
    long pos = (long)j * 63489 + (long)kp * 512;
    return ((size_t)bb * T_LEN + (size_t)pos) * 8u;
}

// 4 fp32 -> 4 bf16 (uint2) via v_cvt_pk_bf16_f32 (RNE)
static __device__ __forceinline__ uint2 cvt4(float4 v) {
    unsigned lo, hi;
    asm("v_cvt_pk_bf16_f32 %0, %1, %2" : "=v"(lo) : "v"(v.x), "v"(v.y));
    asm("v_cvt_pk_bf16_f32 %0, %1, %2" : "=v"(hi) : "v"(v.z), "v"(v.w));
    uint2 u; u.x = lo; u.y = hi;
    return u;
}

// ---------------------------------------------------------------------------
// Kernel 1 (R11, proven): repack weights fragment-major (16x16 MFMA) with
// per-col-group gate pairing. uint4 chunk c = (((ks*2+kq)*2+nf)*8+g)*64 + l:
//   n = nf==0 ? g*16+(l&15) : 128+g*16+(l&15)
//   k = ks*64 + kq*32 + (l>>4)*8 + 0..7
//   W'[n][k] = (n<128?w1:w2)[n&127][e=k&7][t=k>>3] as bf16. Init outu.
// ---------------------------------------------------------------------------
__global__ __launch_bounds__(256) void pack_w(const float* __restrict__ w1,
                                              const float* __restrict__ w2,
                                              uint4* __restrict__ Bpf,
                                              unsigned* __restrict__ outu) {
    int c = blockIdx.x * 256 + threadIdx.x;         // grid 512 -> 131072
    if (c < 512) outu[c] = 0u;
    if (c >= 131072) return;
    int l  = c & 63;
    int g  = (c >> 6) & 7;
    int nf = (c >> 9) & 1;
    int kq = (c >> 10) & 1;
    int ks = c >> 11;
    int n  = nf ? (128 + g * 16 + (l & 15)) : (g * 16 + (l & 15));
    int kb = ks * 64 + kq * 32 + ((l >> 4) << 3);
    const float* src = (n < 128) ? w1 : w2;
    int cc = n & 127;
    unsigned short h[8];
#pragma unroll
    for (int j = 0; j < 8; ++j) {
        int k = kb + j;
        h[j] = f2bf(src[cc * 4096 + (k & 7) * 512 + (k >> 3)]);
    }
    uint4 v;
    v.x = (unsigned)h[0] | ((unsigned)h[1] << 16);
    v.y = (unsigned)h[2] | ((unsigned)h[3] << 16);
    v.z = (unsigned)h[4] | ((unsigned)h[5] << 16);
    v.w = (unsigned)h[6] | ((unsigned)h[7] << 16);
    Bpf[c] = v;
}

// ---------------------------------------------------------------------------
// Kernel 2: GEMM + gate + max. 512 thr / 8 waves; wave w owns rows 0..31 and
// col-group g=w (cols {g*16..+15} c1 | {128+g*16..+15} c2). acc[2][2].
// A ring-8 in LDS (8 x 4KB). Superstep = 2 K-tiles, lgkmcnt(14)+s_barrier.
// ---------------------------------------------------------------------------
#define LOAD_B(BB, KS)                                                         \
    do {                                                                       \
        _Pragma("unroll")                                                      \
        for (int kq = 0; kq < 2; ++kq)                                         \
            _Pragma("unroll")                                                  \
            for (int nf = 0; nf < 2; ++nf)                                     \
                BB[kq][nf] = Bq[((KS) * 4 + kq * 2 + nf) * 512 + bbase];       \
    } while (0)

// One K-tile, NO barrier. Loads A for tile KS+6, writes tile KS+4's slot.
#define STEP_NB(KS, BCUR, BNXT)                                                \
    do {                                                                       \
        const int ks_ = (KS);                                                  \
        const int ksn = (ks_ + 1 < 64) ? ks_ + 1 : 63;                         \
        LOAD_B(BNXT, ksn);                                                     \
        const int ksl = (ks_ + 6 < 64) ? ks_ + 6 : 63;                         \
        float4 aF = *(const float4*)(x + aoff + (size_t)(ksl * 64));           \
        const char* As = smem + (ks_ & 7) * 4096;                              \
        _Pragma("unroll")                                                      \
        for (int kq = 0; kq < 2; ++kq) {                                       \
            short8 af0 = *(const short8*)(As + aro[kq][0]);                    \
            short8 af1 = *(const short8*)(As + aro[kq][1]);                    \
            short8 b0  = __builtin_bit_cast(short8, BCUR[kq][0]);              \
            short8 b1  = __builtin_bit_cast(short8, BCUR[kq][1]);              \
            acc[0][0] = __builtin_amdgcn_mfma_f32_16x16x32_bf16(               \
                af0, b0, acc[0][0], 0, 0, 0);                                  \
            acc[1][0] = __builtin_amdgcn_mfma_f32_16x16x32_bf16(               \
                af1, b0, acc[1][0], 0, 0, 0);                                  \
            acc[0][1] = __builtin_amdgcn_mfma_f32_16x16x32_bf16(               \
                af0, b1, acc[0][1], 0, 0, 0);                                  \
            acc[1][1] = __builtin_amdgcn_mfma_f32_16x16x32_bf16(               \
                af1, b1, acc[1][1], 0, 0, 0);                                  \
        }                                                                      \
        if (ks_ + 4 < 64)                                                      \
            *(uint2*)(smem + ((ks_ + 4) & 7) * 4096 + awb) = cvt4(aA);         \
        aA = aB; aB = aF;                                                      \
    } while (0)

__global__ __launch_bounds__(512, 4) void gemm_max(const float* __restrict__ x,
                                                   const uint4* __restrict__ Bq,
                                                   const float* __restrict__ b1,
                                                   const float* __restrict__ b2,
                                                   unsigned* __restrict__ outu) {
    __shared__ __align__(16) char smem[32768];      // ring-8 of 4KB

    const int t    = threadIdx.x;
    const int lane = t & 63;
    const int g    = t >> 6;                        // wave = col-group 0..7
    const int bid  = blockIdx.x;
    const int bb   = bid / 124;                     // batch (block-uniform)
    const int p0   = (bid % 124) * 32;              // first position of block

    // ---- A staging: thread t handles row=t>>4 (0..31), k-chunk t&15 ----
    const int rowS = t >> 4;
    const int kcS  = t & 15;
    int pS = p0 + rowS; if (pS > P_CNT - 1) pS = P_CNT - 1;
    const size_t aoff = row_base_bp(bb, pS) + (size_t)(kcS * 4);
    const int    awb  = (rowS * 128 + kcS * 8) ^ ((rowS & 7) << 4);

    // ---- A fragment read offsets [kq][mf] (XOR-swizzled, 2-way-free) ----
    int aro[2][2];
#pragma unroll
    for (int kq = 0; kq < 2; ++kq)
#pragma unroll
        for (int mf = 0; mf < 2; ++mf) {
            int row = mf * 16 + (lane & 15);
            aro[kq][mf] = (row * 128 + kq * 64 + (lane >> 4) * 16)
                          ^ ((row & 7) << 4);
        }

    const int bbase = g * 64 + lane;                // uint4 units

    // ---- prologue: stage tiles 0..3 into slots 0..3 ----
#pragma unroll
    for (int pt = 0; pt < 4; ++pt) {
        float4 v = *(const float4*)(x + aoff + pt * 64);
        *(uint2*)(smem + pt * 4096 + awb) = cvt4(v);
    }
    __syncthreads();

    float4 aA = *(const float4*)(x + aoff + 256);   // tile 4
    float4 aB = *(const float4*)(x + aoff + 320);   // tile 5
    uint4 BX[2][2], BY[2][2];
    LOAD_B(BX, 0);

    f32x4 acc[2][2];
#pragma unroll
    for (int mf = 0; mf < 2; ++mf)
#pragma unroll
        for (int nf = 0; nf < 2; ++nf) acc[mf][nf] = (f32x4){0.f, 0.f, 0.f, 0.f};

    // ---- main loop: 32 supersteps of 2 K-tiles, one counted barrier each.
    // Publish proof: write(slot s+4) at step s has 5 newer DS ops in its own
    // superstep + 10 in the next = 15 newer by the 2nd barrier; lgkmcnt(14)
    // forces <=14 outstanding => write retired before its read at step s+4.
    // Intra-superstep: writes hit slots s+4/s+5, reads s/s+1 (disjoint mod 8).
    for (int ks = 0; ks < 64; ks += 2) {
        STEP_NB(ks, BX, BY);
        STEP_NB(ks + 1, BY, BX);
        asm volatile("s_waitcnt lgkmcnt(14)" ::: "memory");
        __builtin_amdgcn_s_barrier();
        asm volatile("" ::: "memory");
    }

    // ---- epilogue: gate pair is same-lane (acc[.][0]=c1, acc[.][1]=c2) ----
    const int   cidx = g * 16 + (lane & 15);
    const float bb1  = b1[cidx];
    const float bb2  = b2[cidx];
    float best = -3.4e38f;
#pragma unroll
    for (int mf = 0; mf < 2; ++mf)
#pragma unroll
        for (int q = 0; q < 4; ++q) {
            float c1 = acc[mf][0][q] + bb1;
            float c2 = acc[mf][1][q] + bb2;
            float gv = c1 / (1.f + __expf(-c2));
            best = fmaxf(best, gv);
        }
    // reduce over row-slots (lane bits 4,5); batch is block-uniform
    best = fmaxf(best, __shfl_xor(best, 16));
    best = fmaxf(best, __shfl_xor(best, 32));
    if (lane < 16)
        atomicMax(&outu[bb * 128 + cidx], ordenc(best));
}

// ---------------------------------------------------------------------------
// Kernel 3: decode order-encoded uints to floats in place.
// ---------------------------------------------------------------------------
__global__ __launch_bounds__(256) void unmap_out(unsigned* __restrict__ outu) {
    int i = blockIdx.x * 256 + threadIdx.x;
    if (i < 512) {
        unsigned u = outu[i];
        outu[i] = (u & 0x80000000u) ? (u ^ 0x80000000u) : ~u;
    }
}

extern "C" void kernel_launch(void* const* d_in, const int* in_sizes, int n_in,
                              void* d_out, int out_size, void* d_ws, size_t ws_size,
                              hipStream_t stream) {
    const float* x  = (const float*)d_in[0];
    const float* w1 = (const float*)d_in[1];
    const float* b1 = (const float*)d_in[2];
    const float* w2 = (const float*)d_in[3];
    const float* b2 = (const float*)d_in[4];

    uint4*    Bpf  = (uint4*)d_ws;                  // 2 MB fragment-major bf16
    unsigned* outu = (unsigned*)d_out;

    pack_w<<<dim3(512), dim3(256), 0, stream>>>(w1, w2, Bpf, outu);

    const int nblk = 124 * 4;                       // 496, batch-aligned
    gemm_max<<<dim3(nblk), dim3(512), 0, stream>>>(x, (const uint4*)Bpf, b1, b2, outu);

    unmap_out<<<dim3(2), dim3(256), 0, stream>>>(outu);
}